// Round 11
// baseline (941.154 us; speedup 1.0000x reference)
//
#include <hip/hip_runtime.h>
#include <hip/hip_bf16.h>
#include <math.h>

// ---------------------------------------------------------------------------
// MambaModel fused forward. GEMMs: bf16 MFMA (pre-converted operands).
// R11: nchunks>=2 (activation arena fits 256MB L3 per chunk);
//      scan: serial exp chain (R9) + prefetched xc registers.
// B=4096, S=9, d=256, H=2, hd=128, di=512, N=16, dtr=16, dcv=4
// ---------------------------------------------------------------------------

#define BATCH 4096

typedef __attribute__((ext_vector_type(8))) short short8;
typedef __attribute__((ext_vector_type(4))) float f32x4;
typedef __attribute__((ext_vector_type(4))) unsigned short u16x4;
typedef unsigned short ushort;

#define GLD16(gp, lp) __builtin_amdgcn_global_load_lds( \
    (const __attribute__((address_space(1))) unsigned int*)(gp), \
    (__attribute__((address_space(3))) unsigned int*)(lp), 16, 0, 0)

__device__ __forceinline__ ushort f2bf(float f) {
    unsigned u = __float_as_uint(f);
    u += 0x7fffu + ((u >> 16) & 1u);   // RNE to bf16
    return (ushort)(u >> 16);
}
__device__ __forceinline__ float bf2f(ushort u) {
    return __uint_as_float(((unsigned)u) << 16);
}

// ---------------- one-shot weight conversion fp32 -> bf16 ------------------
__global__ __launch_bounds__(256) void convw_kernel(
    const float* __restrict__ s0, const float* __restrict__ s1,
    const float* __restrict__ s2, const float* __restrict__ s3,
    const float* __restrict__ s4, const float* __restrict__ s5,
    ushort* __restrict__ dst)
{
    int i = blockIdx.x * 256 + threadIdx.x;
    float v;
    if      (i < 393216)  v = s0[i];
    else if (i < 524288)  v = s1[i - 393216];
    else if (i < 655360)  v = s2[i - 524288];
    else if (i < 786432)  v = s3[i - 655360];
    else if (i < 1048576) v = s4[i - 786432];
    else                  v = s5[i - 1048576];
    dst[i] = f2bf(v);
}

// ---------------- embed: h = x * w1 + b1 (fp32 + bf16 copy) ----------------
__global__ __launch_bounds__(256) void embed_kernel(
    const float* __restrict__ x, const float* __restrict__ w1,
    const float* __restrict__ b1, float* __restrict__ h,
    ushort* __restrict__ hbf, int r0, int nr)
{
    int i = blockIdx.x * 256 + threadIdx.x;
    if (i >= nr * 256) return;
    int c  = i & 255;
    int row = i >> 8;
    float v = x[r0 + row] * w1[c] + b1[c];
    h[i] = v;
    hbf[i] = f2bf(v);
}

// ---------------- MFMA GEMM, bf16 operands ---------------------------------
// Staging: global_load_lds width=16, swizzle applied on SOURCE address.
// outmode: 0 -> Cf fp32 ; 1 -> Cb bf16 ; 2 -> gate: Cb = bf16(yin * v*sig(v))
__global__ __launch_bounds__(256) void mgemm_kernel(
    const ushort* __restrict__ A, const ushort* __restrict__ W,
    const float* __restrict__ bias, float* __restrict__ Cf,
    ushort* __restrict__ Cb, const float* __restrict__ yin,
    int M, int N, int K, int lda, int act, int outmode)
{
    __shared__ ushort As[128 * 64];   // [row][k], 8-elt slots; slot ^= row&7
    __shared__ ushort Bs[128 * 64];

    const int tid  = threadIdx.x;
    const int m0   = blockIdx.x * 128;
    const int n0   = blockIdx.y * 128;
    const int wid  = tid >> 6, lane = tid & 63;
    const int wr   = wid >> 1, wc = wid & 1;
    const int lrow = lane & 15, lk8 = lane >> 4, l7 = lane & 7;
    const int rw   = lane >> 3, sl8 = lane & 7;   // staging: 8 rows x 8 slots

    f32x4 acc[4][4];
    #pragma unroll
    for (int i = 0; i < 4; ++i)
        #pragma unroll
        for (int j = 0; j < 4; ++j)
            acc[i][j] = f32x4{0.f, 0.f, 0.f, 0.f};

    for (int k0 = 0; k0 < K; k0 += 64) {
        const int ka = (sl8 ^ rw) * 8;    // pre-swizzled source slot
        #pragma unroll
        for (int p = 0; p < 4; ++p) {
            const int r0 = (p * 4 + wid) * 8;
            const int r  = r0 + rw;
            GLD16(&A[(size_t)(m0 + r) * lda + k0 + ka], &As[r0 * 64]);
            GLD16(&W[(size_t)(n0 + r) * K   + k0 + ka], &Bs[r0 * 64]);
        }
        __syncthreads();

        #pragma unroll
        for (int kh = 0; kh < 2; ++kh) {
            short8 af[4], bf[4];
            #pragma unroll
            for (int i = 0; i < 4; ++i) {
                const int ra = wr * 64 + i * 16 + lrow;
                const int rb = wc * 64 + i * 16 + lrow;
                const int sl = ((kh << 2) | lk8) ^ l7;
                af[i] = *reinterpret_cast<const short8*>(&As[ra * 64 + sl * 8]);
                bf[i] = *reinterpret_cast<const short8*>(&Bs[rb * 64 + sl * 8]);
            }
            #pragma unroll
            for (int i = 0; i < 4; ++i)
                #pragma unroll
                for (int j = 0; j < 4; ++j)
                    acc[i][j] = __builtin_amdgcn_mfma_f32_16x16x32_bf16(
                        af[i], bf[j], acc[i][j], 0, 0, 0);
        }
        __syncthreads();
    }

    const int cb = n0 + wc * 64 + lrow;
    const int rb = m0 + wr * 64 + lk8 * 4;
    float bj[4];
    #pragma unroll
    for (int j = 0; j < 4; ++j) bj[j] = bias ? bias[cb + j * 16] : 0.f;

    #pragma unroll
    for (int i = 0; i < 4; ++i) {
        #pragma unroll
        for (int r = 0; r < 4; ++r) {
            const size_t mrow = (size_t)(rb + i * 16 + r) * N;
            #pragma unroll
            for (int j = 0; j < 4; ++j) {
                float v = acc[i][j][r] + bj[j];
                const size_t idx = mrow + cb + j * 16;
                if (act == 1) v = fmaxf(v, 0.f);
                if (outmode == 0) {
                    Cf[idx] = v;
                } else if (outmode == 1) {
                    Cb[idx] = f2bf(v);
                } else {
                    const float sig = 1.f / (1.f + __expf(-v));
                    Cb[idx] = f2bf(yin[idx] * (v * sig));
                }
            }
        }
    }
}

// ---------------- fp32 SGEMM for small/odd shapes --------------------------
__global__ __launch_bounds__(256) void sgemm_kernel(
    const float* __restrict__ A, const float* __restrict__ W,
    const float* __restrict__ bias, float* __restrict__ C,
    int M, int N, int K, int lda, int act)
{
    __shared__ float As[16][68];
    __shared__ float Ws[16][68];
    const int tid = threadIdx.x;
    const int m0 = blockIdx.y * 64;
    const int n0 = blockIdx.x * 64;
    const int tm = tid >> 4;
    const int tn = tid & 15;
    const int lrow = tid >> 2;
    const int lk   = (tid & 3) * 4;

    float acc[4][4] = {};

    for (int k0 = 0; k0 < K; k0 += 16) {
        {
            int m = m0 + lrow;
            float4 v = make_float4(0.f, 0.f, 0.f, 0.f);
            if (m < M) v = *reinterpret_cast<const float4*>(&A[(size_t)m * lda + k0 + lk]);
            As[lk + 0][lrow] = v.x; As[lk + 1][lrow] = v.y;
            As[lk + 2][lrow] = v.z; As[lk + 3][lrow] = v.w;
            int n = n0 + lrow;
            float4 w = make_float4(0.f, 0.f, 0.f, 0.f);
            if (n < N) w = *reinterpret_cast<const float4*>(&W[(size_t)n * K + k0 + lk]);
            Ws[lk + 0][lrow] = w.x; Ws[lk + 1][lrow] = w.y;
            Ws[lk + 2][lrow] = w.z; Ws[lk + 3][lrow] = w.w;
        }
        __syncthreads();
        #pragma unroll
        for (int k = 0; k < 16; ++k) {
            float4 av = *reinterpret_cast<const float4*>(&As[k][tm * 4]);
            float4 wv = *reinterpret_cast<const float4*>(&Ws[k][tn * 4]);
            float a[4] = {av.x, av.y, av.z, av.w};
            float w[4] = {wv.x, wv.y, wv.z, wv.w};
            #pragma unroll
            for (int i = 0; i < 4; ++i)
                #pragma unroll
                for (int j = 0; j < 4; ++j)
                    acc[i][j] = fmaf(a[i], w[j], acc[i][j]);
        }
        __syncthreads();
    }

    #pragma unroll
    for (int i = 0; i < 4; ++i) {
        int m = m0 + tm * 4 + i;
        if (m >= M) continue;
        #pragma unroll
        for (int j = 0; j < 4; ++j) {
            int n = n0 + tn * 4 + j;
            if (n >= N) continue;
            float v = acc[i][j];
            if (bias) v += bias[n];
            if (act == 1) v = fmaxf(v, 0.f);
            C[(size_t)m * N + n] = v;
        }
    }
}

// ---------------- attention per (b_local, head): S=9, hd=128, bf16 in ------
__global__ __launch_bounds__(128) void attn_kernel(
    const ushort* __restrict__ qkv, ushort* __restrict__ o, int nb)
{
    __shared__ float q[9][132], kk[9][132], v[9][132];
    __shared__ float sc[9][12];
    const int blk = blockIdx.x;
    if (blk >= nb * 2) return;
    const int b = blk >> 1, head = blk & 1;
    const int t = threadIdx.x;
    const size_t base = (size_t)b * 9 * 768 + (size_t)head * 128;
    #pragma unroll
    for (int s = 0; s < 9; ++s) {
        q[s][t]  = bf2f(qkv[base + s * 768 + t]);
        kk[s][t] = bf2f(qkv[base + s * 768 + 256 + t]);
        v[s][t]  = bf2f(qkv[base + s * 768 + 512 + t]);
    }
    __syncthreads();
    if (t < 81) {
        int qi = t / 9, ki = t % 9;
        float acc = 0.f;
        #pragma unroll 8
        for (int c = 0; c < 128; ++c) acc = fmaf(q[qi][c], kk[ki][c], acc);
        sc[qi][ki] = acc * 0.08838834764831845f;
    }
    __syncthreads();
    if (t < 9) {
        float mx = -1e30f;
        #pragma unroll
        for (int k2 = 0; k2 < 9; ++k2) mx = fmaxf(mx, sc[t][k2]);
        float e[9], sum = 0.f;
        #pragma unroll
        for (int k2 = 0; k2 < 9; ++k2) { e[k2] = __expf(sc[t][k2] - mx); sum += e[k2]; }
        float inv = 1.f / sum;
        #pragma unroll
        for (int k2 = 0; k2 < 9; ++k2) sc[t][k2] = e[k2] * inv;
    }
    __syncthreads();
    #pragma unroll
    for (int qi = 0; qi < 9; ++qi) {
        float acc = 0.f;
        #pragma unroll
        for (int k2 = 0; k2 < 9; ++k2) acc = fmaf(sc[qi][k2], v[k2][t], acc);
        o[(size_t)(b * 9 + qi) * 256 + head * 128 + t] = f2bf(acc);
    }
}

// ---------------- residual add + LayerNorm, wave per row -------------------
__global__ __launch_bounds__(256) void ln_add_kernel(
    const float* __restrict__ h, const float* __restrict__ a,
    const float* __restrict__ g, const float* __restrict__ bb,
    float* __restrict__ out, ushort* __restrict__ outbf, int nrows)
{
    const int wave = threadIdx.x >> 6;
    const int lane = threadIdx.x & 63;
    const int row = blockIdx.x * 4 + wave;
    if (row >= nrows) return;
    const float4 hv = reinterpret_cast<const float4*>(h + (size_t)row * 256)[lane];
    const float4 av = reinterpret_cast<const float4*>(a + (size_t)row * 256)[lane];
    float x0 = hv.x + av.x, x1 = hv.y + av.y, x2 = hv.z + av.z, x3 = hv.w + av.w;
    float s  = x0 + x1 + x2 + x3;
    float sq = x0 * x0 + x1 * x1 + x2 * x2 + x3 * x3;
    #pragma unroll
    for (int off = 32; off; off >>= 1) {
        s  += __shfl_down(s, off);
        sq += __shfl_down(sq, off);
    }
    s = __shfl(s, 0); sq = __shfl(sq, 0);
    const float mean = s * (1.f / 256.f);
    const float var  = sq * (1.f / 256.f) - mean * mean;
    const float inv  = rsqrtf(var + 1e-5f);
    const float4 gv = reinterpret_cast<const float4*>(g)[lane];
    const float4 bv = reinterpret_cast<const float4*>(bb)[lane];
    float4 ov;
    ov.x = (x0 - mean) * inv * gv.x + bv.x;
    ov.y = (x1 - mean) * inv * gv.y + bv.y;
    ov.z = (x2 - mean) * inv * gv.z + bv.z;
    ov.w = (x3 - mean) * inv * gv.w + bv.w;
    reinterpret_cast<float4*>(out + (size_t)row * 256)[lane] = ov;
    u16x4 bf;
    bf.x = f2bf(ov.x); bf.y = f2bf(ov.y); bf.z = f2bf(ov.z); bf.w = f2bf(ov.w);
    reinterpret_cast<u16x4*>(outbf + (size_t)row * 256)[lane] = bf;
}

// ---------------- conv+silu v2: thread per (b,c), xm fetched once ----------
__global__ __launch_bounds__(256) void conv_silu2_kernel(
    const float* __restrict__ xm, const float* __restrict__ cw,
    const float* __restrict__ cb, float* __restrict__ xc, int nb)
{
    int i = blockIdx.x * 256 + threadIdx.x;   // over nb*512
    if (i >= nb * 512) return;
    const int c = i & 511, b = i >> 9;
    float xmv[9];
    #pragma unroll
    for (int s = 0; s < 9; ++s)
        xmv[s] = xm[(size_t)(b * 9 + s) * 512 + c];
    const float4 cwv4 = *reinterpret_cast<const float4*>(&cw[c * 4]);
    const float cwv[4] = {cwv4.x, cwv4.y, cwv4.z, cwv4.w};
    const float cbv = cb[c];
    #pragma unroll
    for (int s = 0; s < 9; ++s) {
        float acc = cbv;
        #pragma unroll
        for (int k = 0; k < 4; ++k) {
            const int sp = s + k - 3;
            if (sp >= 0) acc = fmaf(cwv[k], xmv[sp], acc);
        }
        const float sig = 1.f / (1.f + __expf(-acc));
        xc[(size_t)(b * 9 + s) * 512 + c] = acc * sig;
    }
}

// ---------------- SSM scan: block per b (512 thr), xdb in LDS --------------
// In place: reads xc, writes y over it. dt fused (softplus).
// R11: xc prefetched to registers; serial e1 power chain (R9 form).
__global__ __launch_bounds__(512) void scan_kernel(
    float* __restrict__ xcy, const float* __restrict__ xdb,
    const float* __restrict__ dt_w, const float* __restrict__ dt_b,
    const float* __restrict__ A_log, const float* __restrict__ Dp)
{
    __shared__ float sx[9 * 48];
    const int c = threadIdx.x;
    const int b = blockIdx.x;
    if (c < 108) {
        reinterpret_cast<float4*>(sx)[c] =
            reinterpret_cast<const float4*>(xdb + (size_t)b * 432)[c];
    }

    // prefetch xc column (9 values, independent loads pipeline)
    float xcv[9];
    #pragma unroll
    for (int s = 0; s < 9; ++s)
        xcv[s] = xcy[(size_t)(b * 9 + s) * 512 + c];

    float wdt[16], Ar[16];
    #pragma unroll
    for (int n = 0; n < 16; n += 4) {
        const float4 wv4 = *reinterpret_cast<const float4*>(&dt_w[c * 16 + n]);
        wdt[n] = wv4.x; wdt[n + 1] = wv4.y; wdt[n + 2] = wv4.z; wdt[n + 3] = wv4.w;
        const float4 av4 = *reinterpret_cast<const float4*>(&A_log[c * 16 + n]);
        Ar[n] = -__expf(av4.x); Ar[n + 1] = -__expf(av4.y);
        Ar[n + 2] = -__expf(av4.z); Ar[n + 3] = -__expf(av4.w);
    }
    const float dtb = dt_b[c];
    const float Dc  = Dp[c];
    const float a1  = Ar[0];
    bool chain = true;
    #pragma unroll
    for (int n = 1; n < 16; ++n)
        chain = chain && (fabsf(Ar[n] - (float)(n + 1) * a1) <=
                          1e-3f * (float)(n + 1) * fabsf(a1));
    __syncthreads();

    float hst[16] = {};
    for (int s = 0; s < 9; ++s) {
        const float* xb = sx + s * 48;
        float dti = dtb;
        #pragma unroll
        for (int n = 0; n < 16; ++n) dti = fmaf(xb[n], wdt[n], dti);
        const float dt = (dti > 20.f) ? dti : __logf(1.f + __expf(dti));
        const float xv = xcv[s];
        const float dtx = dt * xv;
        float acc = 0.f;
        if (chain) {
            const float e1 = __expf(dt * a1);
            float en = 1.f;
            #pragma unroll
            for (int n = 0; n < 16; ++n) {
                en *= e1;
                hst[n] = fmaf(hst[n], en, dtx * xb[16 + n]);
                acc = fmaf(hst[n], xb[32 + n], acc);
            }
        } else {
            #pragma unroll
            for (int n = 0; n < 16; ++n) {
                hst[n] = fmaf(hst[n], __expf(dt * Ar[n]), dtx * xb[16 + n]);
                acc = fmaf(hst[n], xb[32 + n], acc);
            }
        }
        xcy[(size_t)(b * 9 + s) * 512 + c] = acc + Dc * xv;
    }
}

// ---------------- final head: (nr,32) -> (nb,9) -> out[b0+b] ---------------
__global__ __launch_bounds__(256) void head_kernel(
    const float* __restrict__ t32, const float* __restrict__ w2b,
    const float* __restrict__ b2b, const float* __restrict__ w3a,
    const float* __restrict__ b3a, const float* __restrict__ w3b,
    const float* __restrict__ b3b, float* __restrict__ out, int b0, int nb)
{
    int b = blockIdx.x * 256 + threadIdx.x;
    if (b >= nb) return;
    float o9[9];
    #pragma unroll
    for (int s = 0; s < 9; ++s) {
        const float* r = t32 + (size_t)(b * 9 + s) * 32;
        float acc = b2b[0];
        #pragma unroll
        for (int k = 0; k < 32; ++k) acc = fmaf(r[k], w2b[k], acc);
        o9[s] = acc;
    }
    float accout = b3b[0];
    #pragma unroll
    for (int j = 0; j < 9; ++j) {
        float rj = b3a[j];
        #pragma unroll
        for (int s = 0; s < 9; ++s) rj = fmaf(o9[s], w3a[j * 9 + s], rj);
        rj = fmaxf(rj, 0.f);
        accout = fmaf(rj, w3b[j], accout);
    }
    out[b0 + b] = accout;
}

// ---------------------------------------------------------------------------
extern "C" void kernel_launch(void* const* d_in, const int* in_sizes, int n_in,
                              void* d_out, int out_size, void* d_ws, size_t ws_size,
                              hipStream_t stream)
{
    const float* x          = (const float*)d_in[0];
    const float* w1         = (const float*)d_in[1];
    const float* b1         = (const float*)d_in[2];
    const float* attn_in_w  = (const float*)d_in[3];
    const float* attn_in_b  = (const float*)d_in[4];
    const float* attn_out_w = (const float*)d_in[5];
    const float* attn_out_b = (const float*)d_in[6];
    const float* ln1_g      = (const float*)d_in[7];
    const float* ln1_b      = (const float*)d_in[8];
    const float* ffw_w1     = (const float*)d_in[9];
    const float* ffw_b1     = (const float*)d_in[10];
    const float* ffw_w2     = (const float*)d_in[11];
    const float* ffw_b2     = (const float*)d_in[12];
    const float* ln2_g      = (const float*)d_in[13];
    const float* ln2_b      = (const float*)d_in[14];
    const float* in_proj_w  = (const float*)d_in[15];
    const float* conv_w     = (const float*)d_in[16];
    const float* conv_b     = (const float*)d_in[17];
    const float* x_proj_w   = (const float*)d_in[18];
    const float* dt_proj_w  = (const float*)d_in[19];
    const float* dt_proj_b  = (const float*)d_in[20];
    const float* A_log      = (const float*)d_in[21];
    const float* Dp         = (const float*)d_in[22];
    const float* out_proj_w = (const float*)d_in[23];
    const float* w2a        = (const float*)d_in[24];
    const float* b2a        = (const float*)d_in[25];
    const float* w2b        = (const float*)d_in[26];
    const float* b2b        = (const float*)d_in[27];
    const float* w3a        = (const float*)d_in[28];
    const float* b3a        = (const float*)d_in[29];
    const float* w3b        = (const float*)d_in[30];
    const float* b3b        = (const float*)d_in[31];
    float* out = (float*)d_out;

    // ---- weight bf16 arena + adaptive chunking ----------------------------
    // nchunks >= 2: per-chunk activation arena ~133 MB fits the 256 MB L3,
    // so producer->consumer tensors stay cache-resident.
    const size_t WB_FLOATS = 589824;          // 1179648 ushorts
    const size_t PER_ROW = 1792;
    int nchunks = 2;
    while (nchunks < 32 &&
           (WB_FLOATS + (size_t)(BATCH / nchunks) * 9 * PER_ROW) * sizeof(float) > ws_size)
        nchunks <<= 1;
    const int nb = BATCH / nchunks;
    const int nr = nb * 9;
    const size_t CAPR = (size_t)nr;

    ushort* WB = (ushort*)d_ws;
    float*  AR = (float*)d_ws + WB_FLOATS;

    ushort* wb_attn_in  = WB;             // +i*196608
    ushort* wb_attn_out = WB + 393216;    // +i*65536
    ushort* wb_ffw1     = WB + 524288;    // +i*65536
    ushort* wb_ffw2     = WB + 655360;    // +i*65536
    ushort* wb_inproj_x = WB + 786432;
    ushort* wb_inproj_z = WB + 917504;
    ushort* wb_outproj  = WB + 1048576;

    hipLaunchKernelGGL(convw_kernel, dim3(1179648 / 256), dim3(256), 0, stream,
                       attn_in_w, attn_out_w, ffw_w1, ffw_w2, in_proj_w,
                       out_proj_w, WB);

    auto gemm = [&](const float* A, const float* W, const float* bias, float* C,
                    int M, int N, int K, int lda, int act) {
        dim3 grid((N + 63) / 64, (M + 63) / 64);
        hipLaunchKernelGGL(sgemm_kernel, grid, dim3(256), 0, stream,
                           A, W, bias, C, M, N, K, lda, act);
    };
    auto mgemm = [&](const ushort* A, const ushort* W, const float* bias,
                     float* Cf, ushort* Cb, const float* yin,
                     int M, int N, int K, int lda, int act, int outmode) {
        dim3 grid(M / 128, N / 128);
        hipLaunchKernelGGL(mgemm_kernel, grid, dim3(256), 0, stream,
                           A, W, bias, Cf, Cb, yin, M, N, K, lda, act, outmode);
    };

    for (int ck = 0; ck < nchunks; ++ck) {
        const int b0 = ck * nb;
        const int r0 = b0 * 9;

        float*  h    = AR;                           // (256 fl) ; later h2
        ushort* hbf  = (ushort*)(AR + CAPR * 256);   // lda 256
        float*  aux  = AR + CAPR * 384;              // (128 fl): aobf | xdb | t32
        ushort* aobf = (ushort*)aux;                 // lda 256
        float*  big  = AR + CAPR * 512;              // (768 fl)
        ushort* qkvb = (ushort*)big;                 // lda 768
        float*  aa   = big;                          // lda 256 (qkvb dead)
        ushort* f1bf = (ushort*)(big + CAPR * 256);  // lda 256
        float*  f2   = big + CAPR * 384;             // lda 256
        float*  xm   = big;                          // lda 512 (mamba)
        ushort* ybf  = (ushort*)(big + CAPR * 512);  // lda 512
        float*  xc   = AR + CAPR * 1280;             // (512 fl) xc then y
        float*  xdb  = aux;                          // lda 48
        float*  h2   = h;
        float*  t32  = aux;                          // lda 32

        hipLaunchKernelGGL(embed_kernel, dim3((nr * 256 + 255) / 256), dim3(256),
                           0, stream, x, w1, b1, h, hbf, r0, nr);

        for (int i = 0; i < 2; ++i) {
            mgemm(hbf, wb_attn_in + (size_t)i * 196608, attn_in_b + i * 768,
                  nullptr, qkvb, nullptr, nr, 768, 256, 256, 0, 1);
            hipLaunchKernelGGL(attn_kernel, dim3(nb * 2), dim3(128), 0, stream,
                               qkvb, aobf, nb);
            mgemm(aobf, wb_attn_out + (size_t)i * 65536, attn_out_b + i * 256,
                  aa, nullptr, nullptr, nr, 256, 256, 256, 0, 0);
            hipLaunchKernelGGL(ln_add_kernel, dim3((nr + 3) / 4), dim3(256), 0, stream,
                               h, aa, ln1_g + i * 256, ln1_b + i * 256, h, hbf, nr);
            mgemm(hbf, wb_ffw1 + (size_t)i * 65536, ffw_b1 + i * 256,
                  nullptr, f1bf, nullptr, nr, 256, 256, 256, 1, 1);
            mgemm(f1bf, wb_ffw2 + (size_t)i * 65536, ffw_b2 + i * 256,
                  f2, nullptr, nullptr, nr, 256, 256, 256, 0, 0);
            hipLaunchKernelGGL(ln_add_kernel, dim3((nr + 3) / 4), dim3(256), 0, stream,
                               h, f2, ln2_g + i * 256, ln2_b + i * 256, h, hbf, nr);
        }

        // ---- Mamba block ----
        mgemm(hbf, wb_inproj_x, nullptr, xm, nullptr, nullptr,
              nr, 512, 256, 256, 0, 0);
        hipLaunchKernelGGL(conv_silu2_kernel, dim3((nb * 512 + 255) / 256), dim3(256),
                           0, stream, xm, conv_w, conv_b, xc, nb);
        gemm(xc, x_proj_w, nullptr, xdb, nr, 48, 512, 512, 0);
        hipLaunchKernelGGL(scan_kernel, dim3(nb), dim3(512), 0, stream,
                           xc, xdb, dt_proj_w, dt_proj_b, A_log, Dp);
        // z-GEMM with fused silu-gate: ybf = bf16(y * z*sig(z))
        mgemm(hbf, wb_inproj_z, nullptr, nullptr, ybf, xc,
              nr, 512, 256, 256, 0, 2);
        mgemm(ybf, wb_outproj, nullptr, h2, nullptr, nullptr,
              nr, 256, 512, 512, 0, 0);
        gemm(h2, w2a, b2a, t32, nr, 32, 256, 256, 0);
        hipLaunchKernelGGL(head_kernel, dim3((nb + 255) / 256), dim3(256), 0, stream,
                           t32, w2b, b2b, w3a, b3a, w3b, b3b, out, b0, nb);
    }
}

// Round 12
// 673.707 us; speedup vs baseline: 1.3970x; 1.3970x over previous
//
#include <hip/hip_runtime.h>
#include <hip/hip_bf16.h>
#include <math.h>

// ---------------------------------------------------------------------------
// MambaModel fused forward. GEMMs: bf16 MFMA (pre-converted operands).
// R12: revert chunking (nchunks auto from 1). Collapse out_proj+w2a+w2b into
//      one 512-dot head (rank-1 algebra). Keep R11 scan (prefetch + chain).
// B=4096, S=9, d=256, H=2, hd=128, di=512, N=16, dtr=16, dcv=4
// ---------------------------------------------------------------------------

#define BATCH 4096

typedef __attribute__((ext_vector_type(8))) short short8;
typedef __attribute__((ext_vector_type(4))) float f32x4;
typedef __attribute__((ext_vector_type(4))) unsigned short u16x4;
typedef unsigned short ushort;

#define GLD16(gp, lp) __builtin_amdgcn_global_load_lds( \
    (const __attribute__((address_space(1))) unsigned int*)(gp), \
    (__attribute__((address_space(3))) unsigned int*)(lp), 16, 0, 0)

__device__ __forceinline__ ushort f2bf(float f) {
    unsigned u = __float_as_uint(f);
    u += 0x7fffu + ((u >> 16) & 1u);   // RNE to bf16
    return (ushort)(u >> 16);
}
__device__ __forceinline__ float bf2f(ushort u) {
    return __uint_as_float(((unsigned)u) << 16);
}

// ---------------- one-shot weight conversion fp32 -> bf16 ------------------
__global__ __launch_bounds__(256) void convw_kernel(
    const float* __restrict__ s0, const float* __restrict__ s1,
    const float* __restrict__ s2, const float* __restrict__ s3,
    const float* __restrict__ s4, const float* __restrict__ s5,
    ushort* __restrict__ dst)
{
    int i = blockIdx.x * 256 + threadIdx.x;
    float v;
    if      (i < 393216)  v = s0[i];
    else if (i < 524288)  v = s1[i - 393216];
    else if (i < 655360)  v = s2[i - 524288];
    else if (i < 786432)  v = s3[i - 655360];
    else if (i < 1048576) v = s4[i - 786432];
    else                  v = s5[i - 1048576];
    dst[i] = f2bf(v);
}

// ---------------- head-weight collapse: wc2 = w2b@w2a@out_proj -------------
// one block, 512 threads. wcb[0..511] = wc2, wcb[512] = bc.
__global__ __launch_bounds__(512) void headw_kernel(
    const float* __restrict__ out_proj_w,  // (256,512)
    const float* __restrict__ w2a,         // (32,256)
    const float* __restrict__ b2a,         // (32)
    const float* __restrict__ w2b,         // (1,32)
    const float* __restrict__ b2b,         // (1)
    float* __restrict__ wcb)
{
    __shared__ float vc[256];
    const int t = threadIdx.x;
    if (t < 256) {
        float a = 0.f;
        #pragma unroll
        for (int j = 0; j < 32; ++j) a = fmaf(w2b[j], w2a[j * 256 + t], a);
        vc[t] = a;
    }
    __syncthreads();
    float a = 0.f;
    for (int c = 0; c < 256; ++c) a = fmaf(vc[c], out_proj_w[c * 512 + t], a);
    wcb[t] = a;
    if (t == 0) {
        float bc = b2b[0];
        #pragma unroll
        for (int j = 0; j < 32; ++j) bc = fmaf(w2b[j], b2a[j], bc);
        wcb[512] = bc;
    }
}

// ---------------- embed: h = x * w1 + b1 (fp32 + bf16 copy) ----------------
__global__ __launch_bounds__(256) void embed_kernel(
    const float* __restrict__ x, const float* __restrict__ w1,
    const float* __restrict__ b1, float* __restrict__ h,
    ushort* __restrict__ hbf, int r0, int nr)
{
    int i = blockIdx.x * 256 + threadIdx.x;
    if (i >= nr * 256) return;
    int c  = i & 255;
    int row = i >> 8;
    float v = x[r0 + row] * w1[c] + b1[c];
    h[i] = v;
    hbf[i] = f2bf(v);
}

// ---------------- MFMA GEMM, bf16 operands ---------------------------------
// Staging: global_load_lds width=16, swizzle applied on SOURCE address.
// outmode: 0 -> Cf fp32 ; 1 -> Cb bf16 ; 2 -> gate: Cb = bf16(yin * v*sig(v))
__global__ __launch_bounds__(256) void mgemm_kernel(
    const ushort* __restrict__ A, const ushort* __restrict__ W,
    const float* __restrict__ bias, float* __restrict__ Cf,
    ushort* __restrict__ Cb, const float* __restrict__ yin,
    int M, int N, int K, int lda, int act, int outmode)
{
    __shared__ ushort As[128 * 64];   // [row][k], 8-elt slots; slot ^= row&7
    __shared__ ushort Bs[128 * 64];

    const int tid  = threadIdx.x;
    const int m0   = blockIdx.x * 128;
    const int n0   = blockIdx.y * 128;
    const int wid  = tid >> 6, lane = tid & 63;
    const int wr   = wid >> 1, wc = wid & 1;
    const int lrow = lane & 15, lk8 = lane >> 4, l7 = lane & 7;
    const int rw   = lane >> 3, sl8 = lane & 7;   // staging: 8 rows x 8 slots

    f32x4 acc[4][4];
    #pragma unroll
    for (int i = 0; i < 4; ++i)
        #pragma unroll
        for (int j = 0; j < 4; ++j)
            acc[i][j] = f32x4{0.f, 0.f, 0.f, 0.f};

    for (int k0 = 0; k0 < K; k0 += 64) {
        const int ka = (sl8 ^ rw) * 8;    // pre-swizzled source slot
        #pragma unroll
        for (int p = 0; p < 4; ++p) {
            const int r0 = (p * 4 + wid) * 8;
            const int r  = r0 + rw;
            GLD16(&A[(size_t)(m0 + r) * lda + k0 + ka], &As[r0 * 64]);
            GLD16(&W[(size_t)(n0 + r) * K   + k0 + ka], &Bs[r0 * 64]);
        }
        __syncthreads();

        #pragma unroll
        for (int kh = 0; kh < 2; ++kh) {
            short8 af[4], bf[4];
            #pragma unroll
            for (int i = 0; i < 4; ++i) {
                const int ra = wr * 64 + i * 16 + lrow;
                const int rb = wc * 64 + i * 16 + lrow;
                const int sl = ((kh << 2) | lk8) ^ l7;
                af[i] = *reinterpret_cast<const short8*>(&As[ra * 64 + sl * 8]);
                bf[i] = *reinterpret_cast<const short8*>(&Bs[rb * 64 + sl * 8]);
            }
            #pragma unroll
            for (int i = 0; i < 4; ++i)
                #pragma unroll
                for (int j = 0; j < 4; ++j)
                    acc[i][j] = __builtin_amdgcn_mfma_f32_16x16x32_bf16(
                        af[i], bf[j], acc[i][j], 0, 0, 0);
        }
        __syncthreads();
    }

    const int cb = n0 + wc * 64 + lrow;
    const int rb = m0 + wr * 64 + lk8 * 4;
    float bj[4];
    #pragma unroll
    for (int j = 0; j < 4; ++j) bj[j] = bias ? bias[cb + j * 16] : 0.f;

    #pragma unroll
    for (int i = 0; i < 4; ++i) {
        #pragma unroll
        for (int r = 0; r < 4; ++r) {
            const size_t mrow = (size_t)(rb + i * 16 + r) * N;
            #pragma unroll
            for (int j = 0; j < 4; ++j) {
                float v = acc[i][j][r] + bj[j];
                const size_t idx = mrow + cb + j * 16;
                if (act == 1) v = fmaxf(v, 0.f);
                if (outmode == 0) {
                    Cf[idx] = v;
                } else if (outmode == 1) {
                    Cb[idx] = f2bf(v);
                } else {
                    const float sig = 1.f / (1.f + __expf(-v));
                    Cb[idx] = f2bf(yin[idx] * (v * sig));
                }
            }
        }
    }
}

// ---------------- fp32 SGEMM for small/odd shapes --------------------------
__global__ __launch_bounds__(256) void sgemm_kernel(
    const float* __restrict__ A, const float* __restrict__ W,
    const float* __restrict__ bias, float* __restrict__ C,
    int M, int N, int K, int lda, int act)
{
    __shared__ float As[16][68];
    __shared__ float Ws[16][68];
    const int tid = threadIdx.x;
    const int m0 = blockIdx.y * 64;
    const int n0 = blockIdx.x * 64;
    const int tm = tid >> 4;
    const int tn = tid & 15;
    const int lrow = tid >> 2;
    const int lk   = (tid & 3) * 4;

    float acc[4][4] = {};

    for (int k0 = 0; k0 < K; k0 += 16) {
        {
            int m = m0 + lrow;
            float4 v = make_float4(0.f, 0.f, 0.f, 0.f);
            if (m < M) v = *reinterpret_cast<const float4*>(&A[(size_t)m * lda + k0 + lk]);
            As[lk + 0][lrow] = v.x; As[lk + 1][lrow] = v.y;
            As[lk + 2][lrow] = v.z; As[lk + 3][lrow] = v.w;
            int n = n0 + lrow;
            float4 w = make_float4(0.f, 0.f, 0.f, 0.f);
            if (n < N) w = *reinterpret_cast<const float4*>(&W[(size_t)n * K + k0 + lk]);
            Ws[lk + 0][lrow] = w.x; Ws[lk + 1][lrow] = w.y;
            Ws[lk + 2][lrow] = w.z; Ws[lk + 3][lrow] = w.w;
        }
        __syncthreads();
        #pragma unroll
        for (int k = 0; k < 16; ++k) {
            float4 av = *reinterpret_cast<const float4*>(&As[k][tm * 4]);
            float4 wv = *reinterpret_cast<const float4*>(&Ws[k][tn * 4]);
            float a[4] = {av.x, av.y, av.z, av.w};
            float w[4] = {wv.x, wv.y, wv.z, wv.w};
            #pragma unroll
            for (int i = 0; i < 4; ++i)
                #pragma unroll
                for (int j = 0; j < 4; ++j)
                    acc[i][j] = fmaf(a[i], w[j], acc[i][j]);
        }
        __syncthreads();
    }

    #pragma unroll
    for (int i = 0; i < 4; ++i) {
        int m = m0 + tm * 4 + i;
        if (m >= M) continue;
        #pragma unroll
        for (int j = 0; j < 4; ++j) {
            int n = n0 + tn * 4 + j;
            if (n >= N) continue;
            float v = acc[i][j];
            if (bias) v += bias[n];
            if (act == 1) v = fmaxf(v, 0.f);
            C[(size_t)m * N + n] = v;
        }
    }
}

// ---------------- attention per (b_local, head): S=9, hd=128, bf16 in ------
__global__ __launch_bounds__(128) void attn_kernel(
    const ushort* __restrict__ qkv, ushort* __restrict__ o, int nb)
{
    __shared__ float q[9][132], kk[9][132], v[9][132];
    __shared__ float sc[9][12];
    const int blk = blockIdx.x;
    if (blk >= nb * 2) return;
    const int b = blk >> 1, head = blk & 1;
    const int t = threadIdx.x;
    const size_t base = (size_t)b * 9 * 768 + (size_t)head * 128;
    #pragma unroll
    for (int s = 0; s < 9; ++s) {
        q[s][t]  = bf2f(qkv[base + s * 768 + t]);
        kk[s][t] = bf2f(qkv[base + s * 768 + 256 + t]);
        v[s][t]  = bf2f(qkv[base + s * 768 + 512 + t]);
    }
    __syncthreads();
    if (t < 81) {
        int qi = t / 9, ki = t % 9;
        float acc = 0.f;
        #pragma unroll 8
        for (int c = 0; c < 128; ++c) acc = fmaf(q[qi][c], kk[ki][c], acc);
        sc[qi][ki] = acc * 0.08838834764831845f;
    }
    __syncthreads();
    if (t < 9) {
        float mx = -1e30f;
        #pragma unroll
        for (int k2 = 0; k2 < 9; ++k2) mx = fmaxf(mx, sc[t][k2]);
        float e[9], sum = 0.f;
        #pragma unroll
        for (int k2 = 0; k2 < 9; ++k2) { e[k2] = __expf(sc[t][k2] - mx); sum += e[k2]; }
        float inv = 1.f / sum;
        #pragma unroll
        for (int k2 = 0; k2 < 9; ++k2) sc[t][k2] = e[k2] * inv;
    }
    __syncthreads();
    #pragma unroll
    for (int qi = 0; qi < 9; ++qi) {
        float acc = 0.f;
        #pragma unroll
        for (int k2 = 0; k2 < 9; ++k2) acc = fmaf(sc[qi][k2], v[k2][t], acc);
        o[(size_t)(b * 9 + qi) * 256 + head * 128 + t] = f2bf(acc);
    }
}

// ---------------- residual add + LayerNorm, wave per row -------------------
__global__ __launch_bounds__(256) void ln_add_kernel(
    const float* __restrict__ h, const float* __restrict__ a,
    const float* __restrict__ g, const float* __restrict__ bb,
    float* __restrict__ out, ushort* __restrict__ outbf, int nrows)
{
    const int wave = threadIdx.x >> 6;
    const int lane = threadIdx.x & 63;
    const int row = blockIdx.x * 4 + wave;
    if (row >= nrows) return;
    const float4 hv = reinterpret_cast<const float4*>(h + (size_t)row * 256)[lane];
    const float4 av = reinterpret_cast<const float4*>(a + (size_t)row * 256)[lane];
    float x0 = hv.x + av.x, x1 = hv.y + av.y, x2 = hv.z + av.z, x3 = hv.w + av.w;
    float s  = x0 + x1 + x2 + x3;
    float sq = x0 * x0 + x1 * x1 + x2 * x2 + x3 * x3;
    #pragma unroll
    for (int off = 32; off; off >>= 1) {
        s  += __shfl_down(s, off);
        sq += __shfl_down(sq, off);
    }
    s = __shfl(s, 0); sq = __shfl(sq, 0);
    const float mean = s * (1.f / 256.f);
    const float var  = sq * (1.f / 256.f) - mean * mean;
    const float inv  = rsqrtf(var + 1e-5f);
    const float4 gv = reinterpret_cast<const float4*>(g)[lane];
    const float4 bv = reinterpret_cast<const float4*>(bb)[lane];
    float4 ov;
    ov.x = (x0 - mean) * inv * gv.x + bv.x;
    ov.y = (x1 - mean) * inv * gv.y + bv.y;
    ov.z = (x2 - mean) * inv * gv.z + bv.z;
    ov.w = (x3 - mean) * inv * gv.w + bv.w;
    reinterpret_cast<float4*>(out + (size_t)row * 256)[lane] = ov;
    u16x4 bf;
    bf.x = f2bf(ov.x); bf.y = f2bf(ov.y); bf.z = f2bf(ov.z); bf.w = f2bf(ov.w);
    reinterpret_cast<u16x4*>(outbf + (size_t)row * 256)[lane] = bf;
}

// ---------------- conv+silu v2: thread per (b,c), xm fetched once ----------
__global__ __launch_bounds__(256) void conv_silu2_kernel(
    const float* __restrict__ xm, const float* __restrict__ cw,
    const float* __restrict__ cb, float* __restrict__ xc, int nb)
{
    int i = blockIdx.x * 256 + threadIdx.x;   // over nb*512
    if (i >= nb * 512) return;
    const int c = i & 511, b = i >> 9;
    float xmv[9];
    #pragma unroll
    for (int s = 0; s < 9; ++s)
        xmv[s] = xm[(size_t)(b * 9 + s) * 512 + c];
    const float4 cwv4 = *reinterpret_cast<const float4*>(&cw[c * 4]);
    const float cwv[4] = {cwv4.x, cwv4.y, cwv4.z, cwv4.w};
    const float cbv = cb[c];
    #pragma unroll
    for (int s = 0; s < 9; ++s) {
        float acc = cbv;
        #pragma unroll
        for (int k = 0; k < 4; ++k) {
            const int sp = s + k - 3;
            if (sp >= 0) acc = fmaf(cwv[k], xmv[sp], acc);
        }
        const float sig = 1.f / (1.f + __expf(-acc));
        xc[(size_t)(b * 9 + s) * 512 + c] = acc * sig;
    }
}

// ---------------- SSM scan: block per b (512 thr), xdb in LDS --------------
__global__ __launch_bounds__(512) void scan_kernel(
    float* __restrict__ xcy, const float* __restrict__ xdb,
    const float* __restrict__ dt_w, const float* __restrict__ dt_b,
    const float* __restrict__ A_log, const float* __restrict__ Dp)
{
    __shared__ float sx[9 * 48];
    const int c = threadIdx.x;
    const int b = blockIdx.x;
    if (c < 108) {
        reinterpret_cast<float4*>(sx)[c] =
            reinterpret_cast<const float4*>(xdb + (size_t)b * 432)[c];
    }

    float xcv[9];
    #pragma unroll
    for (int s = 0; s < 9; ++s)
        xcv[s] = xcy[(size_t)(b * 9 + s) * 512 + c];

    float wdt[16], Ar[16];
    #pragma unroll
    for (int n = 0; n < 16; n += 4) {
        const float4 wv4 = *reinterpret_cast<const float4*>(&dt_w[c * 16 + n]);
        wdt[n] = wv4.x; wdt[n + 1] = wv4.y; wdt[n + 2] = wv4.z; wdt[n + 3] = wv4.w;
        const float4 av4 = *reinterpret_cast<const float4*>(&A_log[c * 16 + n]);
        Ar[n] = -__expf(av4.x); Ar[n + 1] = -__expf(av4.y);
        Ar[n + 2] = -__expf(av4.z); Ar[n + 3] = -__expf(av4.w);
    }
    const float dtb = dt_b[c];
    const float Dc  = Dp[c];
    const float a1  = Ar[0];
    bool chain = true;
    #pragma unroll
    for (int n = 1; n < 16; ++n)
        chain = chain && (fabsf(Ar[n] - (float)(n + 1) * a1) <=
                          1e-3f * (float)(n + 1) * fabsf(a1));
    __syncthreads();

    float hst[16] = {};
    for (int s = 0; s < 9; ++s) {
        const float* xb = sx + s * 48;
        float dti = dtb;
        #pragma unroll
        for (int n = 0; n < 16; ++n) dti = fmaf(xb[n], wdt[n], dti);
        const float dt = (dti > 20.f) ? dti : __logf(1.f + __expf(dti));
        const float xv = xcv[s];
        const float dtx = dt * xv;
        float acc = 0.f;
        if (chain) {
            const float e1 = __expf(dt * a1);
            float en = 1.f;
            #pragma unroll
            for (int n = 0; n < 16; ++n) {
                en *= e1;
                hst[n] = fmaf(hst[n], en, dtx * xb[16 + n]);
                acc = fmaf(hst[n], xb[32 + n], acc);
            }
        } else {
            #pragma unroll
            for (int n = 0; n < 16; ++n) {
                hst[n] = fmaf(hst[n], __expf(dt * Ar[n]), dtx * xb[16 + n]);
                acc = fmaf(hst[n], xb[32 + n], acc);
            }
        }
        xcy[(size_t)(b * 9 + s) * 512 + c] = acc + Dc * xv;
    }
}

// ---------------- fused head: wave per b; dot(ybf_row, wc2) -> 9->1 MLP ----
__global__ __launch_bounds__(256) void head2_kernel(
    const ushort* __restrict__ ybf, const float* __restrict__ wcb,
    const float* __restrict__ w3a, const float* __restrict__ b3a,
    const float* __restrict__ w3b, const float* __restrict__ b3b,
    float* __restrict__ out, int b0, int nb)
{
    const int wave = threadIdx.x >> 6, lane = threadIdx.x & 63;
    const int b = blockIdx.x * 4 + wave;
    if (b >= nb) return;

    // per-lane slice of the collapsed 512-weight vector
    float wreg[8];
    {
        const float4 w0 = *reinterpret_cast<const float4*>(&wcb[lane * 8]);
        const float4 w1 = *reinterpret_cast<const float4*>(&wcb[lane * 8 + 4]);
        wreg[0] = w0.x; wreg[1] = w0.y; wreg[2] = w0.z; wreg[3] = w0.w;
        wreg[4] = w1.x; wreg[5] = w1.y; wreg[6] = w1.z; wreg[7] = w1.w;
    }
    const float bc = wcb[512];

    float o9[9];
    #pragma unroll
    for (int s = 0; s < 9; ++s) {
        const short8 yv = *reinterpret_cast<const short8*>(
            &ybf[(size_t)(b * 9 + s) * 512 + lane * 8]);
        float acc = 0.f;
        #pragma unroll
        for (int k = 0; k < 8; ++k)
            acc = fmaf(bf2f((ushort)yv[k]), wreg[k], acc);
        #pragma unroll
        for (int off = 32; off; off >>= 1) acc += __shfl_down(acc, off);
        o9[s] = __shfl(acc, 0) + bc;
    }
    if (lane == 0) {
        float accout = b3b[0];
        #pragma unroll
        for (int j = 0; j < 9; ++j) {
            float rj = b3a[j];
            #pragma unroll
            for (int s = 0; s < 9; ++s) rj = fmaf(o9[s], w3a[j * 9 + s], rj);
            rj = fmaxf(rj, 0.f);
            accout = fmaf(rj, w3b[j], accout);
        }
        out[b0 + b] = accout;
    }
}

// ---------------------------------------------------------------------------
extern "C" void kernel_launch(void* const* d_in, const int* in_sizes, int n_in,
                              void* d_out, int out_size, void* d_ws, size_t ws_size,
                              hipStream_t stream)
{
    const float* x          = (const float*)d_in[0];
    const float* w1         = (const float*)d_in[1];
    const float* b1         = (const float*)d_in[2];
    const float* attn_in_w  = (const float*)d_in[3];
    const float* attn_in_b  = (const float*)d_in[4];
    const float* attn_out_w = (const float*)d_in[5];
    const float* attn_out_b = (const float*)d_in[6];
    const float* ln1_g      = (const float*)d_in[7];
    const float* ln1_b      = (const float*)d_in[8];
    const float* ffw_w1     = (const float*)d_in[9];
    const float* ffw_b1     = (const float*)d_in[10];
    const float* ffw_w2     = (const float*)d_in[11];
    const float* ffw_b2     = (const float*)d_in[12];
    const float* ln2_g      = (const float*)d_in[13];
    const float* ln2_b      = (const float*)d_in[14];
    const float* in_proj_w  = (const float*)d_in[15];
    const float* conv_w     = (const float*)d_in[16];
    const float* conv_b     = (const float*)d_in[17];
    const float* x_proj_w   = (const float*)d_in[18];
    const float* dt_proj_w  = (const float*)d_in[19];
    const float* dt_proj_b  = (const float*)d_in[20];
    const float* A_log      = (const float*)d_in[21];
    const float* Dp         = (const float*)d_in[22];
    const float* out_proj_w = (const float*)d_in[23];
    const float* w2a        = (const float*)d_in[24];
    const float* b2a        = (const float*)d_in[25];
    const float* w2b        = (const float*)d_in[26];
    const float* b2b        = (const float*)d_in[27];
    const float* w3a        = (const float*)d_in[28];
    const float* b3a        = (const float*)d_in[29];
    const float* w3b        = (const float*)d_in[30];
    const float* b3b        = (const float*)d_in[31];
    float* out = (float*)d_out;

    // ---- weight bf16 arena + collapsed head weights + adaptive chunking ---
    const size_t WB_FLOATS = 589824;          // 1179648 ushorts
    const size_t HW_FLOATS = 1024;            // wc2[512] + bc + pad
    const size_t PER_ROW = 1792;
    int nchunks = 1;
    while (nchunks < 32 &&
           (WB_FLOATS + HW_FLOATS +
            (size_t)(BATCH / nchunks) * 9 * PER_ROW) * sizeof(float) > ws_size)
        nchunks <<= 1;
    const int nb = BATCH / nchunks;
    const int nr = nb * 9;
    const size_t CAPR = (size_t)nr;

    ushort* WB  = (ushort*)d_ws;
    float*  wcb = (float*)d_ws + WB_FLOATS;
    float*  AR  = wcb + HW_FLOATS;

    ushort* wb_attn_in  = WB;             // +i*196608
    ushort* wb_attn_out = WB + 393216;    // +i*65536
    ushort* wb_ffw1     = WB + 524288;    // +i*65536
    ushort* wb_ffw2     = WB + 655360;    // +i*65536
    ushort* wb_inproj_x = WB + 786432;
    ushort* wb_inproj_z = WB + 917504;

    hipLaunchKernelGGL(convw_kernel, dim3(1179648 / 256), dim3(256), 0, stream,
                       attn_in_w, attn_out_w, ffw_w1, ffw_w2, in_proj_w,
                       out_proj_w, WB);
    hipLaunchKernelGGL(headw_kernel, dim3(1), dim3(512), 0, stream,
                       out_proj_w, w2a, b2a, w2b, b2b, wcb);

    auto gemm = [&](const float* A, const float* W, const float* bias, float* C,
                    int M, int N, int K, int lda, int act) {
        dim3 grid((N + 63) / 64, (M + 63) / 64);
        hipLaunchKernelGGL(sgemm_kernel, grid, dim3(256), 0, stream,
                           A, W, bias, C, M, N, K, lda, act);
    };
    auto mgemm = [&](const ushort* A, const ushort* W, const float* bias,
                     float* Cf, ushort* Cb, const float* yin,
                     int M, int N, int K, int lda, int act, int outmode) {
        dim3 grid(M / 128, N / 128);
        hipLaunchKernelGGL(mgemm_kernel, grid, dim3(256), 0, stream,
                           A, W, bias, Cf, Cb, yin, M, N, K, lda, act, outmode);
    };

    for (int ck = 0; ck < nchunks; ++ck) {
        const int b0 = ck * nb;
        const int r0 = b0 * 9;

        float*  h    = AR;                           // (256 fl)
        ushort* hbf  = (ushort*)(AR + CAPR * 256);   // lda 256
        float*  aux  = AR + CAPR * 384;              // (128 fl): aobf | xdb
        ushort* aobf = (ushort*)aux;                 // lda 256
        float*  big  = AR + CAPR * 512;              // (768 fl)
        ushort* qkvb = (ushort*)big;                 // lda 768
        float*  aa   = big;                          // lda 256 (qkvb dead)
        ushort* f1bf = (ushort*)(big + CAPR * 256);  // lda 256
        float*  f2   = big + CAPR * 384;             // lda 256
        float*  xm   = big;                          // lda 512 (mamba)
        ushort* ybf  = (ushort*)(big + CAPR * 512);  // lda 512
        float*  xc   = AR + CAPR * 1280;             // (512 fl) xc then y
        float*  xdb  = aux;                          // lda 48

        hipLaunchKernelGGL(embed_kernel, dim3((nr * 256 + 255) / 256), dim3(256),
                           0, stream, x, w1, b1, h, hbf, r0, nr);

        for (int i = 0; i < 2; ++i) {
            mgemm(hbf, wb_attn_in + (size_t)i * 196608, attn_in_b + i * 768,
                  nullptr, qkvb, nullptr, nr, 768, 256, 256, 0, 1);
            hipLaunchKernelGGL(attn_kernel, dim3(nb * 2), dim3(128), 0, stream,
                               qkvb, aobf, nb);
            mgemm(aobf, wb_attn_out + (size_t)i * 65536, attn_out_b + i * 256,
                  aa, nullptr, nullptr, nr, 256, 256, 256, 0, 0);
            hipLaunchKernelGGL(ln_add_kernel, dim3((nr + 3) / 4), dim3(256), 0, stream,
                               h, aa, ln1_g + i * 256, ln1_b + i * 256, h, hbf, nr);
            mgemm(hbf, wb_ffw1 + (size_t)i * 65536, ffw_b1 + i * 256,
                  nullptr, f1bf, nullptr, nr, 256, 256, 256, 1, 1);
            mgemm(f1bf, wb_ffw2 + (size_t)i * 65536, ffw_b2 + i * 256,
                  f2, nullptr, nullptr, nr, 256, 256, 256, 0, 0);
            hipLaunchKernelGGL(ln_add_kernel, dim3((nr + 3) / 4), dim3(256), 0, stream,
                               h, f2, ln2_g + i * 256, ln2_b + i * 256, h, hbf, nr);
        }

        // ---- Mamba block ----
        mgemm(hbf, wb_inproj_x, nullptr, xm, nullptr, nullptr,
              nr, 512, 256, 256, 0, 0);
        hipLaunchKernelGGL(conv_silu2_kernel, dim3((nb * 512 + 255) / 256), dim3(256),
                           0, stream, xm, conv_w, conv_b, xc, nb);
        gemm(xc, x_proj_w, nullptr, xdb, nr, 48, 512, 512, 0);
        hipLaunchKernelGGL(scan_kernel, dim3(nb), dim3(512), 0, stream,
                           xc, xdb, dt_proj_w, dt_proj_b, A_log, Dp);
        // z-GEMM with fused silu-gate: ybf = bf16(y * z*sig(z))
        mgemm(hbf, wb_inproj_z, nullptr, nullptr, ybf, xc,
              nr, 512, 256, 256, 0, 2);
        // collapsed head: out = MLP9(dot(ybf_row, wc2) + bc)
        hipLaunchKernelGGL(head2_kernel, dim3((nb + 3) / 4), dim3(256), 0, stream,
                           ybf, wcb, w3a, b3a, w3b, b3b, out, b0, nb);
    }
}